// Round 1
// baseline (496.982 us; speedup 1.0000x reference)
//
#include <hip/hip_runtime.h>
#include <stdint.h>

// Problem constants
#define NODES   64
#define FDIM    256
#define ODIM    256
#define BGRAPH  4096
#define TROWS   (NODES * BGRAPH)   // 262144

// GEMM tile
#define BM 64
#define BN 256
#define BK 32

typedef short  bf16x8  __attribute__((ext_vector_type(8)));
typedef float  floatx4 __attribute__((ext_vector_type(4)));

// RTNE fp32 -> bf16 (values are finite gaussians; no NaN handling needed)
__device__ inline unsigned short f2bf(float f) {
    unsigned int u = __float_as_uint(f);
    return (unsigned short)((u + 0x7fffu + ((u >> 16) & 1u)) >> 16);
}

// ---------------------------------------------------------------------------
// Kernel 1: W [node][f][o] fp32  ->  Wt [node][o][f] bf16, scale 1/16 folded.
// grid (16, 64), block 256. 64x64 tiles via padded LDS.
// ---------------------------------------------------------------------------
__global__ __launch_bounds__(256) void transpose_w(const float* __restrict__ W,
                                                   unsigned short* __restrict__ Wt) {
    __shared__ unsigned short t[64][65];
    const int node = blockIdx.y;
    const int tf = (blockIdx.x >> 2) << 6;   // f tile origin
    const int to = (blockIdx.x & 3) << 6;    // o tile origin
    const int tid = threadIdx.x;
    const float* Wn = W + node * (FDIM * ODIM);
#pragma unroll
    for (int i = 0; i < 16; ++i) {
        int flat = i * 256 + tid;
        int r = flat >> 6, c = flat & 63;    // r = f_local, c = o_local (coalesced in o)
        float v = Wn[(tf + r) * ODIM + (to + c)] * 0.0625f;
        t[c][r] = f2bf(v);
    }
    __syncthreads();
    unsigned short* Wtn = Wt + node * (FDIM * ODIM);
#pragma unroll
    for (int i = 0; i < 16; ++i) {
        int flat = i * 256 + tid;
        int r = flat >> 6, c = flat & 63;    // r = o_local, c = f_local (coalesced in f)
        Wtn[(to + r) * FDIM + (tf + c)] = t[r][c];
    }
}

// ---------------------------------------------------------------------------
// Kernel 2: per-node GEMM. out[(b*64+node)*256 + o] = sum_f x[(b*64+node)*256+f] * Wt[node][o][f]
// block: 256 threads = 4 waves in 2x2; each wave 32x128 via 2x8 mfma_f32_16x16x32_bf16.
// A: fp32 global -> cvt -> LDS [BM][BK]; B: global_load_lds (bf16, 16B/lane) -> LDS [BN][BK].
// ---------------------------------------------------------------------------
__global__ __launch_bounds__(256) void gemm_node(const float* __restrict__ x,
                                                 const unsigned short* __restrict__ Wt,
                                                 float* __restrict__ out) {
    __shared__ unsigned short As[BM * BK];   // [row][k], 4 KB
    __shared__ unsigned short Bs[BN * BK];   // [o][k], 16 KB

    const int mblk = blockIdx.x;             // 0..63  (batch tile)
    const int node = blockIdx.y;             // 0..63
    const int tid  = threadIdx.x;
    const int lane = tid & 63;
    const int wave = tid >> 6;               // 0..3
    const int wm   = wave >> 1;              // 0..1 -> 32 rows
    const int wn   = wave & 1;               // 0..1 -> 128 cols
    const int b0   = mblk * BM;

    const int l15 = lane & 15;
    const int l4  = lane >> 4;               // 0..3

    floatx4 acc[2][8] = {};

    // A staging addresses: thread handles 2 float4 chunks per K-step
    // idx in [0,512): row = idx>>3 (0..63), ch = idx&7 (0..7) -> 4 floats each
    const int arow0 = tid >> 3;              // idx = tid
    const int ach0  = tid & 7;
    const int arow1 = (256 + tid) >> 3;
    const int ach1  = (256 + tid) & 7;
    const float* aptr0 = x + (((size_t)(b0 + arow0) * NODES + node) * FDIM + ach0 * 4);
    const float* aptr1 = x + (((size_t)(b0 + arow1) * NODES + node) * FDIM + ach1 * 4);

    const unsigned short* wt_node = Wt + (size_t)node * (ODIM * FDIM);

    for (int kt = 0; kt < 8; ++kt) {
        const int k0 = kt * BK;
        __syncthreads();   // previous iter's frag reads complete before overwrite

        // ---- stage A (fp32 -> bf16 -> LDS) ----
        {
            float4 v0 = *(const float4*)(aptr0 + k0);
            float4 v1 = *(const float4*)(aptr1 + k0);
            ushort4 p0, p1;
            p0.x = f2bf(v0.x); p0.y = f2bf(v0.y); p0.z = f2bf(v0.z); p0.w = f2bf(v0.w);
            p1.x = f2bf(v1.x); p1.y = f2bf(v1.y); p1.z = f2bf(v1.z); p1.w = f2bf(v1.w);
            *(ushort4*)(&As[arow0 * BK + ach0 * 4]) = p0;
            *(ushort4*)(&As[arow1 * BK + ach1 * 4]) = p1;
        }

        // ---- stage B (async global -> LDS, 1 KB per wave-instr) ----
#pragma unroll
        for (int j = 0; j < 4; ++j) {
            const int slot_base = (wave * 4 + j) * 64;       // wave-uniform
            const int slot = slot_base + lane;               // 16B slot index
            const unsigned short* g =
                wt_node + ((size_t)(slot >> 2) * FDIM + k0 + (slot & 3) * 8);
            __builtin_amdgcn_global_load_lds(
                (const __attribute__((address_space(1))) void*)g,
                (__attribute__((address_space(3))) void*)(&Bs[slot_base * 8]),
                16, 0, 0);
        }

        __syncthreads();   // drains vmcnt (global_load_lds) + lgkmcnt (ds_write)

        // ---- fragments + MFMA ----
        bf16x8 a[2], b[8];
#pragma unroll
        for (int mi = 0; mi < 2; ++mi)
            a[mi] = *(const bf16x8*)(&As[(wm * 32 + mi * 16 + l15) * BK + l4 * 8]);
#pragma unroll
        for (int ni = 0; ni < 8; ++ni)
            b[ni] = *(const bf16x8*)(&Bs[(wn * 128 + ni * 16 + l15) * BK + l4 * 8]);
#pragma unroll
        for (int mi = 0; mi < 2; ++mi)
#pragma unroll
            for (int ni = 0; ni < 8; ++ni)
                acc[mi][ni] = __builtin_amdgcn_mfma_f32_16x16x32_bf16(a[mi], b[ni], acc[mi][ni], 0, 0, 0);
    }

    // ---- epilogue: C/D layout col = lane&15, row = (lane>>4)*4 + reg ----
#pragma unroll
    for (int mi = 0; mi < 2; ++mi) {
#pragma unroll
        for (int ni = 0; ni < 8; ++ni) {
            const int row_base = b0 + wm * 32 + mi * 16 + l4 * 4;
            const int col = wn * 128 + ni * 16 + l15;
#pragma unroll
            for (int r = 0; r < 4; ++r) {
                out[((size_t)(row_base + r) * NODES + node) * ODIM + col] = acc[mi][ni][r];
            }
        }
    }
}

// ---------------------------------------------------------------------------
// Fallback (only if ws too small): fp32 naive, one block per output row.
// ---------------------------------------------------------------------------
__global__ __launch_bounds__(256) void naive_kernel(const float* __restrict__ x,
                                                    const float* __restrict__ W,
                                                    float* __restrict__ out) {
    __shared__ float xs[FDIM];
    const int row = blockIdx.x;
    const int node = row & (NODES - 1);
    const int o = threadIdx.x;
    xs[o] = x[(size_t)row * FDIM + o];
    __syncthreads();
    const float* Wn = W + (size_t)node * FDIM * ODIM;
    float s = 0.f;
#pragma unroll 8
    for (int f = 0; f < FDIM; ++f) s += xs[f] * Wn[(size_t)f * ODIM + o];
    out[(size_t)row * ODIM + o] = s * 0.0625f;
}

extern "C" void kernel_launch(void* const* d_in, const int* in_sizes, int n_in,
                              void* d_out, int out_size, void* d_ws, size_t ws_size,
                              hipStream_t stream) {
    const float* x = (const float*)d_in[0];
    // d_in[1] = batch (int64) — implied by row layout, unused
    const float* W = (const float*)d_in[2];
    float* out = (float*)d_out;

    const size_t wt_bytes = (size_t)NODES * ODIM * FDIM * sizeof(unsigned short); // 8.4 MB
    if (ws_size >= wt_bytes) {
        unsigned short* Wt = (unsigned short*)d_ws;
        transpose_w<<<dim3(16, NODES), 256, 0, stream>>>(W, Wt);
        gemm_node<<<dim3(BGRAPH / BM, NODES), 256, 0, stream>>>(x, Wt, out);
    } else {
        naive_kernel<<<dim3(TROWS), 256, 0, stream>>>(x, W, out);
    }
}

// Round 2
// 464.159 us; speedup vs baseline: 1.0707x; 1.0707x over previous
//
#include <hip/hip_runtime.h>
#include <stdint.h>

// Problem constants
#define NODES   64
#define FDIM    256
#define ODIM    256
#define BGRAPH  4096
#define TROWS   (NODES * BGRAPH)   // 262144

// GEMM tile
#define BM 128
#define BN 256
#define BK 32
#define ASTRIDE 40   // ushorts per A-row in LDS (32 data + 8 pad -> 80 B stride, conflict-free)

typedef short  bf16x8  __attribute__((ext_vector_type(8)));
typedef float  floatx4 __attribute__((ext_vector_type(4)));

// RTNE fp32 -> bf16
__device__ inline unsigned short f2bf(float f) {
    unsigned int u = __float_as_uint(f);
    return (unsigned short)((u + 0x7fffu + ((u >> 16) & 1u)) >> 16);
}

// ---------------------------------------------------------------------------
// Kernel 1: W [node][f][o] fp32 -> Wt [node][o][f] bf16, 1/16 folded.
// ---------------------------------------------------------------------------
__global__ __launch_bounds__(256) void transpose_w(const float* __restrict__ W,
                                                   unsigned short* __restrict__ Wt) {
    __shared__ unsigned short t[64][65];
    const int node = blockIdx.y;
    const int tf = (blockIdx.x >> 2) << 6;
    const int to = (blockIdx.x & 3) << 6;
    const int tid = threadIdx.x;
    const float* Wn = W + node * (FDIM * ODIM);
#pragma unroll
    for (int i = 0; i < 16; ++i) {
        int flat = i * 256 + tid;
        int r = flat >> 6, c = flat & 63;
        float v = Wn[(tf + r) * ODIM + (to + c)] * 0.0625f;
        t[c][r] = f2bf(v);
    }
    __syncthreads();
    unsigned short* Wtn = Wt + node * (FDIM * ODIM);
#pragma unroll
    for (int i = 0; i < 16; ++i) {
        int flat = i * 256 + tid;
        int r = flat >> 6, c = flat & 63;
        Wtn[(to + r) * FDIM + (tf + c)] = t[r][c];
    }
}

// ---------------------------------------------------------------------------
// Kernel 2: per-node GEMM, BM=128 x BN=256, BK=32, double-buffered LDS.
// 256 threads = 4 waves (2m x 2n); wave tile 64x128 = 4x8 mfma_16x16x32_bf16.
// Bs: XOR-swizzled k-chunks (global_load_lds can't pad); As: 80 B row stride.
// Single __syncthreads per K-step; prefetch of kt+1 overlaps MFMA of kt.
// ---------------------------------------------------------------------------
__global__ __launch_bounds__(256, 2) void gemm_node(const float* __restrict__ x,
                                                    const unsigned short* __restrict__ Wt,
                                                    float* __restrict__ out) {
    __shared__ unsigned short As[2][BM * ASTRIDE];  // 2 x 10 KB
    __shared__ unsigned short Bs[2][BN * BK];       // 2 x 16 KB

    // XCD-aware decode: blocks sharing a node land on the same XCD (L2 reuse)
    const int bid  = blockIdx.x;            // 0..2047
    const int xcd  = bid & 7;
    const int jj   = bid >> 3;              // 0..255
    const int node = xcd * 8 + (jj & 7);    // 8 nodes per XCD
    const int mblk = jj >> 3;               // 0..31
    const int b0   = mblk * BM;

    const int tid  = threadIdx.x;
    const int lane = tid & 63;
    const int wave = tid >> 6;
    const int wm   = wave >> 1;             // 0..1 -> 64 rows
    const int wn   = wave & 1;              // 0..1 -> 128 cols
    const int l15  = lane & 15;
    const int l4   = lane >> 4;

    const float* xblk = x + ((size_t)b0 * NODES + node) * FDIM;      // + row*16384 + k
    const unsigned short* wt_node = Wt + (size_t)node * (ODIM * FDIM);

    // A staging: 1024 float4-chunks per K-step; thread q = i*256+tid: row=q>>3, ch=q&7
    int arow[4], ach[4];
    size_t aoff[4];
#pragma unroll
    for (int i = 0; i < 4; ++i) {
        int q = i * 256 + tid;
        arow[i] = q >> 3;
        ach[i]  = q & 7;
        aoff[i] = (size_t)arow[i] * (NODES * FDIM) + ach[i] * 4;
    }

    floatx4 acc[4][8] = {};
    float4 av[4];

    // ---- prologue: stage kt=0 ----
#pragma unroll
    for (int i = 0; i < 4; ++i) av[i] = *(const float4*)(xblk + aoff[i]);
#pragma unroll
    for (int j = 0; j < 4; ++j) {
        const int slot_base = (wave * 4 + j) * 64;
        const int s = slot_base + lane;
        const int o = s >> 2, c = s & 3;
        const int jg = c ^ ((o >> 1) & 3);
        const unsigned short* g = wt_node + (size_t)o * FDIM + jg * 8;
        __builtin_amdgcn_global_load_lds(
            (const __attribute__((address_space(1))) void*)g,
            (__attribute__((address_space(3))) void*)(&Bs[0][slot_base * 8]),
            16, 0, 0);
    }
#pragma unroll
    for (int i = 0; i < 4; ++i) {
        ushort4 p;
        p.x = f2bf(av[i].x); p.y = f2bf(av[i].y); p.z = f2bf(av[i].z); p.w = f2bf(av[i].w);
        *(ushort4*)(&As[0][arow[i] * ASTRIDE + ach[i] * 4]) = p;
    }
    __syncthreads();

#pragma unroll
    for (int kt = 0; kt < 8; ++kt) {
        const int cur = kt & 1, nxt = cur ^ 1;
        const int k1 = (kt + 1) * BK;

        // ---- prefetch kt+1 (overlaps with this step's compute) ----
        if (kt < 7) {
#pragma unroll
            for (int i = 0; i < 4; ++i) av[i] = *(const float4*)(xblk + aoff[i] + k1);
#pragma unroll
            for (int j = 0; j < 4; ++j) {
                const int slot_base = (wave * 4 + j) * 64;
                const int s = slot_base + lane;
                const int o = s >> 2, c = s & 3;
                const int jg = c ^ ((o >> 1) & 3);
                const unsigned short* g = wt_node + (size_t)o * FDIM + k1 + jg * 8;
                __builtin_amdgcn_global_load_lds(
                    (const __attribute__((address_space(1))) void*)g,
                    (__attribute__((address_space(3))) void*)(&Bs[nxt][slot_base * 8]),
                    16, 0, 0);
            }
        }

        // ---- fragments from cur buffers ----
        bf16x8 a[4], b[8];
#pragma unroll
        for (int mi = 0; mi < 4; ++mi) {
            const int m = wm * 64 + mi * 16 + l15;
            a[mi] = *(const bf16x8*)(&As[cur][m * ASTRIDE + l4 * 8]);
        }
#pragma unroll
        for (int ni = 0; ni < 8; ++ni) {
            const int n = wn * 128 + ni * 16 + l15;
            b[ni] = *(const bf16x8*)(&Bs[cur][n * 32 + (l4 ^ ((n >> 1) & 3)) * 8]);
        }

        // ---- MFMA ----
#pragma unroll
        for (int mi = 0; mi < 4; ++mi)
#pragma unroll
            for (int ni = 0; ni < 8; ++ni)
                acc[mi][ni] = __builtin_amdgcn_mfma_f32_16x16x32_bf16(a[mi], b[ni], acc[mi][ni], 0, 0, 0);

        // ---- write prefetched A into nxt, then barrier ----
        if (kt < 7) {
#pragma unroll
            for (int i = 0; i < 4; ++i) {
                ushort4 p;
                p.x = f2bf(av[i].x); p.y = f2bf(av[i].y); p.z = f2bf(av[i].z); p.w = f2bf(av[i].w);
                *(ushort4*)(&As[nxt][arow[i] * ASTRIDE + ach[i] * 4]) = p;
            }
            __syncthreads();
        }
    }

    // ---- epilogue: C/D layout col = lane&15, row = (lane>>4)*4 + reg ----
    float* outblk = out + ((size_t)b0 * NODES + node) * ODIM;
#pragma unroll
    for (int mi = 0; mi < 4; ++mi) {
        const int row_base = wm * 64 + mi * 16 + l4 * 4;
#pragma unroll
        for (int ni = 0; ni < 8; ++ni) {
            const int col = wn * 128 + ni * 16 + l15;
#pragma unroll
            for (int r = 0; r < 4; ++r) {
                outblk[(size_t)(row_base + r) * (NODES * ODIM) + col] = acc[mi][ni][r];
            }
        }
    }
}

// ---------------------------------------------------------------------------
// Fallback (only if ws too small): fp32 naive.
// ---------------------------------------------------------------------------
__global__ __launch_bounds__(256) void naive_kernel(const float* __restrict__ x,
                                                    const float* __restrict__ W,
                                                    float* __restrict__ out) {
    __shared__ float xs[FDIM];
    const int row = blockIdx.x;
    const int node = row & (NODES - 1);
    const int o = threadIdx.x;
    xs[o] = x[(size_t)row * FDIM + o];
    __syncthreads();
    const float* Wn = W + (size_t)node * FDIM * ODIM;
    float s = 0.f;
#pragma unroll 8
    for (int f = 0; f < FDIM; ++f) s += xs[f] * Wn[(size_t)f * ODIM + o];
    out[(size_t)row * ODIM + o] = s * 0.0625f;
}

extern "C" void kernel_launch(void* const* d_in, const int* in_sizes, int n_in,
                              void* d_out, int out_size, void* d_ws, size_t ws_size,
                              hipStream_t stream) {
    const float* x = (const float*)d_in[0];
    // d_in[1] = batch (int64) — implied by row layout, unused
    const float* W = (const float*)d_in[2];
    float* out = (float*)d_out;

    const size_t wt_bytes = (size_t)NODES * ODIM * FDIM * sizeof(unsigned short); // 8.4 MB
    if (ws_size >= wt_bytes) {
        unsigned short* Wt = (unsigned short*)d_ws;
        transpose_w<<<dim3(16, NODES), 256, 0, stream>>>(W, Wt);
        gemm_node<<<dim3((BGRAPH / BM) * NODES), 256, 0, stream>>>(x, Wt, out);
    } else {
        naive_kernel<<<dim3(TROWS), 256, 0, stream>>>(x, W, out);
    }
}